// Round 1
// baseline (337.093 us; speedup 1.0000x reference)
//
#include <hip/hip_runtime.h>
#include <math.h>

// Problem constants (fixed by harness)
#define BB   32
#define LL   8192
#define CC   32
#define NTOK 1023      // (L-16)/8 + 1
#define KK   16
#define HID  32

// ---------------- K1: per-(b,c) partial sums over an L/8 slice ----------------
// grid = B*8 blocks, block = 256 (g = tid>>5 in 0..7, c = tid&31)
__global__ void k1_partial(const float* __restrict__ x,
                           float* __restrict__ ps, float* __restrict__ pq) {
    int b  = blockIdx.x >> 3;
    int sl = blockIdx.x & 7;
    int c  = threadIdx.x & 31;
    int g  = threadIdx.x >> 5;
    const float* xb = x + (size_t)b * LL * CC;
    float s = 0.f, q = 0.f;
    int l0 = sl * 1024;
    for (int l = l0 + g; l < l0 + 1024; l += 8) {
        float v = xb[(size_t)l * CC + c];
        s += v; q += v * v;
    }
    __shared__ float ls[256], lq[256];
    ls[threadIdx.x] = s; lq[threadIdx.x] = q;
    __syncthreads();
    for (int off = 128; off >= 32; off >>= 1) {
        if (threadIdx.x < off) {
            ls[threadIdx.x] += ls[threadIdx.x + off];
            lq[threadIdx.x] += lq[threadIdx.x + off];
        }
        __syncthreads();
    }
    if (threadIdx.x < 32) {
        ps[blockIdx.x * 32 + c] = ls[c];
        pq[blockIdx.x * 32 + c] = lq[c];
    }
}

// ---------------- K1b: finish global stats, 1 block of 1024 ----------------
__global__ void k1b_final(const float* __restrict__ ps, const float* __restrict__ pq,
                          float* __restrict__ mu_g, float* __restrict__ rstd_g) {
    int t = threadIdx.x;           // t = b*32 + c
    int b = t >> 5, c = t & 31;
    float s = 0.f, q = 0.f;
    for (int sl = 0; sl < 8; ++sl) {
        s += ps[(b * 8 + sl) * 32 + c];
        q += pq[(b * 8 + sl) * 32 + c];
    }
    float mu  = s * (1.0f / LL);
    float var = fmaxf(q * (1.0f / LL) - mu * mu, 1e-4f);
    mu_g[t]   = mu;
    rstd_g[t] = 1.0f / sqrtf(var);
}

// ---------------- K2: token-local stats ----------------
// grid = B*128 (128 = ceil(N/8)), block = 256 (nl = tid>>5, c = tid&31)
__global__ void k2_tok(const float* __restrict__ x,
                       float* __restrict__ mu_l, float* __restrict__ rstd_l) {
    int nb = blockIdx.x & 127;
    int b  = blockIdx.x >> 7;
    int c  = threadIdx.x & 31;
    int nl = threadIdx.x >> 5;
    int n  = nb * 8 + nl;
    if (n >= NTOK) return;
    const float* xp = x + ((size_t)b * LL + n * 8) * CC + c;
    float s = 0.f, q = 0.f;
#pragma unroll
    for (int p = 0; p < 16; ++p) {
        float v = xp[(size_t)p * CC];
        s += v; q += v * v;
    }
    float mu  = s * (1.0f / 16.0f);
    float var = fmaxf(q * (1.0f / 16.0f) - mu * mu, 1e-4f);
    int o = (b * NTOK + n) * CC + c;
    mu_l[o]   = mu;
    rstd_l[o] = 1.0f / sqrtf(var);
}

// ---------------- K3: alpha gate MLP (beta is dead code in the reference) ----
// row = (b*C + c)*N + n ; 4 rows per thread; grid = R/1024 = 1023, block = 256
__global__ void k3_alpha(const float* __restrict__ ff,
                         const float* __restrict__ w1, const float* __restrict__ b1,
                         const float* __restrict__ w2, const float* __restrict__ b2,
                         float* __restrict__ alpha) {
    __shared__ float w1s[KK * HID];
    __shared__ float b1s[HID];
    __shared__ float w2s[HID];
    __shared__ float b2s;
    int t = threadIdx.x;
    for (int i = t; i < KK * HID; i += 256) w1s[i] = w1[i];
    if (t < HID) { b1s[t] = b1[t]; w2s[t] = w2[t]; }
    if (t == 0)  b2s = b2[0];
    __syncthreads();

    int base = blockIdx.x * 1024 + t;   // rows base + 256*r, r=0..3
    float f[4][KK];
#pragma unroll
    for (int r = 0; r < 4; ++r) {
        const float4* p = (const float4*)(ff + (size_t)(base + 256 * r) * KK);
#pragma unroll
        for (int v = 0; v < 4; ++v) {
            float4 x4 = p[v];
            f[r][v * 4 + 0] = x4.x; f[r][v * 4 + 1] = x4.y;
            f[r][v * 4 + 2] = x4.z; f[r][v * 4 + 3] = x4.w;
        }
    }
    float out0 = b2s, out1 = b2s, out2 = b2s, out3 = b2s;
#pragma unroll
    for (int j = 0; j < HID; ++j) {
        float h0 = b1s[j], h1 = b1s[j], h2 = b1s[j], h3 = b1s[j];
#pragma unroll
        for (int k = 0; k < KK; ++k) {
            float w = w1s[k * HID + j];
            h0 += f[0][k] * w; h1 += f[1][k] * w;
            h2 += f[2][k] * w; h3 += f[3][k] * w;
        }
        float wj = w2s[j];
        // exact (erf) gelu, matching approximate=False
        out0 += 0.5f * h0 * (1.0f + erff(h0 * 0.70710678118654752f)) * wj;
        out1 += 0.5f * h1 * (1.0f + erff(h1 * 0.70710678118654752f)) * wj;
        out2 += 0.5f * h2 * (1.0f + erff(h2 * 0.70710678118654752f)) * wj;
        out3 += 0.5f * h3 * (1.0f + erff(h3 * 0.70710678118654752f)) * wj;
    }
    alpha[base          ] = 1.0f / (1.0f + expf(-out0));
    alpha[base + 256    ] = 1.0f / (1.0f + expf(-out1));
    alpha[base + 512    ] = 1.0f / (1.0f + expf(-out2));
    alpha[base + 768    ] = 1.0f / (1.0f + expf(-out3));
}

// ---------------- K4: fused normalize + mix + affine ----------------
// idx = ((b*L)+l)*C + c ; grid = B*L*C/256 = 32768, block = 256
__global__ void k4_main(const float* __restrict__ x,
                        const float* __restrict__ mu_g, const float* __restrict__ rstd_g,
                        const float* __restrict__ mu_l, const float* __restrict__ rstd_l,
                        const float* __restrict__ alpha,
                        const float* __restrict__ scale, const float* __restrict__ bias,
                        float* __restrict__ out) {
    int idx = blockIdx.x * 256 + threadIdx.x;
    int c = idx & 31;
    int l = (idx >> 5) & (LL - 1);
    int b = idx >> 18;                  // 2^18 = L*C
    // tok_per_time closed form (argmin over centers 8n+8, first-index ties)
    int n = (l >= 5) ? min((l - 5) >> 3, NTOK - 1) : 0;

    float xv  = x[idx];
    int gbc   = b * 32 + c;
    float xg  = (xv - mu_g[gbc]) * rstd_g[gbc];
    int o     = (b * NTOK + n) * CC + c;
    float xl  = (xv - mu_l[o]) * rstd_l[o];
    xg = fminf(fmaxf(xg, -30.0f), 30.0f);
    xl = fminf(fmaxf(xl, -30.0f), 30.0f);
    float a   = alpha[gbc * NTOK + n];  // [b][c][n] layout
    float y   = a * xl + (1.0f - a) * xg;
    out[idx]  = y * scale[c] + bias[c];
}

extern "C" void kernel_launch(void* const* d_in, const int* in_sizes, int n_in,
                              void* d_out, int out_size, void* d_ws, size_t ws_size,
                              hipStream_t stream) {
    const float* x    = (const float*)d_in[0];
    const float* ff   = (const float*)d_in[1];
    const float* aw1  = (const float*)d_in[2];
    const float* ab1  = (const float*)d_in[3];
    const float* aw2  = (const float*)d_in[4];
    const float* ab2  = (const float*)d_in[5];
    // d_in[6..9] = beta weights: dead code in the reference output
    const float* scal = (const float*)d_in[10];
    const float* bias = (const float*)d_in[11];
    float* out = (float*)d_out;

    float* wsf    = (float*)d_ws;
    float* ps     = wsf;                       //  8192
    float* pq     = wsf + 8192;                //  8192
    float* mu_g   = wsf + 16384;               //  1024
    float* rstd_g = wsf + 17408;               //  1024
    float* mu_l   = wsf + 18432;               //  1047552
    float* rstd_l = wsf + 18432 + 1047552;     //  1047552
    float* alpha  = wsf + 18432 + 2 * 1047552; //  1047552
    // total 3,161,088 floats = 12.06 MB of d_ws

    k1_partial<<<BB * 8, 256, 0, stream>>>(x, ps, pq);
    k1b_final<<<1, 1024, 0, stream>>>(ps, pq, mu_g, rstd_g);
    k2_tok<<<BB * 128, 256, 0, stream>>>(x, mu_l, rstd_l);
    k3_alpha<<<1023, 256, 0, stream>>>(ff, aw1, ab1, aw2, ab2, alpha);
    k4_main<<<32768, 256, 0, stream>>>(x, mu_g, rstd_g, mu_l, rstd_l, alpha,
                                       scal, bias, out);
}

// Round 2
// 115.882 us; speedup vs baseline: 2.9089x; 2.9089x over previous
//
#include <hip/hip_runtime.h>
#include <math.h>

// Problem constants (fixed by harness)
#define BB   32
#define LL   8192
#define CC   32
#define NTOK 1023      // (L-16)/8 + 1
#define KK   16
#define HID  32

// ---------------- K1: per-(b,c) partial sums over an L/8 slice ----------------
// grid = B*8 blocks, block = 256 (g = tid>>5 in 0..7, c = tid&31)
__global__ void k1_partial(const float* __restrict__ x,
                           float* __restrict__ ps, float* __restrict__ pq) {
    int b  = blockIdx.x >> 3;
    int sl = blockIdx.x & 7;
    int c  = threadIdx.x & 31;
    int g  = threadIdx.x >> 5;
    const float* xb = x + (size_t)b * LL * CC;
    float s = 0.f, q = 0.f;
    int l0 = sl * 1024;
    for (int l = l0 + g; l < l0 + 1024; l += 8) {
        float v = xb[(size_t)l * CC + c];
        s += v; q += v * v;
    }
    __shared__ float ls[256], lq[256];
    ls[threadIdx.x] = s; lq[threadIdx.x] = q;
    __syncthreads();
    for (int off = 128; off >= 32; off >>= 1) {
        if (threadIdx.x < off) {
            ls[threadIdx.x] += ls[threadIdx.x + off];
            lq[threadIdx.x] += lq[threadIdx.x + off];
        }
        __syncthreads();
    }
    if (threadIdx.x < 32) {
        ps[blockIdx.x * 32 + c] = ls[c];
        pq[blockIdx.x * 32 + c] = lq[c];
    }
}

// ---------------- K1b: finish global stats, 1 block of 1024 ----------------
__global__ void k1b_final(const float* __restrict__ ps, const float* __restrict__ pq,
                          float* __restrict__ mu_g, float* __restrict__ rstd_g) {
    int t = threadIdx.x;           // t = b*32 + c
    int b = t >> 5, c = t & 31;
    float s = 0.f, q = 0.f;
    for (int sl = 0; sl < 8; ++sl) {
        s += ps[(b * 8 + sl) * 32 + c];
        q += pq[(b * 8 + sl) * 32 + c];
    }
    float mu  = s * (1.0f / LL);
    float var = fmaxf(q * (1.0f / LL) - mu * mu, 1e-4f);
    mu_g[t]   = mu;
    rstd_g[t] = 1.0f / sqrtf(var);
}

// ---------------- K2: token-local stats ----------------
// grid = B*128 (128 = ceil(N/8)), block = 256 (nl = tid>>5, c = tid&31)
__global__ void k2_tok(const float* __restrict__ x,
                       float* __restrict__ mu_l, float* __restrict__ rstd_l) {
    int nb = blockIdx.x & 127;
    int b  = blockIdx.x >> 7;
    int c  = threadIdx.x & 31;
    int nl = threadIdx.x >> 5;
    int n  = nb * 8 + nl;
    if (n >= NTOK) return;
    const float* xp = x + ((size_t)b * LL + n * 8) * CC + c;
    float s = 0.f, q = 0.f;
#pragma unroll
    for (int p = 0; p < 16; ++p) {
        float v = xp[(size_t)p * CC];
        s += v; q += v * v;
    }
    float mu  = s * (1.0f / 16.0f);
    float var = fmaxf(q * (1.0f / 16.0f) - mu * mu, 1e-4f);
    int o = (b * NTOK + n) * CC + c;
    mu_l[o]   = mu;
    rstd_l[o] = 1.0f / sqrtf(var);
}

// ---------------- K3: alpha gate MLP (beta is dead code in the reference) ----
// ONE row per thread: f[16] stays in registers (the 4-row version spilled:
// VGPR_Count=64 forced f[4][16] to scratch -> 380 MB spill traffic, 285us).
// row = (b*C + c)*N + n ; grid = R/256 = 4092 blocks, block = 256
__global__ void __launch_bounds__(256)
k3_alpha(const float* __restrict__ ff,
         const float* __restrict__ w1, const float* __restrict__ b1,
         const float* __restrict__ w2, const float* __restrict__ b2,
         float* __restrict__ alpha) {
    __shared__ float w1s[KK * HID];
    __shared__ float b1s[HID];
    __shared__ float w2s[HID];
    __shared__ float b2s;
    int t = threadIdx.x;
    for (int i = t; i < KK * HID; i += 256) w1s[i] = w1[i];
    if (t < HID) { b1s[t] = b1[t]; w2s[t] = w2[t]; }
    if (t == 0)  b2s = b2[0];
    __syncthreads();

    int row = blockIdx.x * 256 + t;     // R = 1,047,552 = 4092*256 exactly
    float f[KK];
    const float4* p = (const float4*)(ff + (size_t)row * KK);
#pragma unroll
    for (int v = 0; v < 4; ++v) {
        float4 x4 = p[v];
        f[v * 4 + 0] = x4.x; f[v * 4 + 1] = x4.y;
        f[v * 4 + 2] = x4.z; f[v * 4 + 3] = x4.w;
    }
    float out = b2s;
#pragma unroll
    for (int j = 0; j < HID; ++j) {
        float h = b1s[j];
#pragma unroll
        for (int k = 0; k < KK; ++k)
            h = fmaf(f[k], w1s[k * HID + j], h);
        // exact (erf) gelu, matching approximate=False
        float g = 0.5f * h * (1.0f + erff(h * 0.70710678118654752f));
        out = fmaf(g, w2s[j], out);
    }
    alpha[row] = 1.0f / (1.0f + expf(-out));
}

// ---------------- K4: fused normalize + mix + affine ----------------
// idx = ((b*L)+l)*C + c ; grid = B*L*C/256 = 32768, block = 256
__global__ void k4_main(const float* __restrict__ x,
                        const float* __restrict__ mu_g, const float* __restrict__ rstd_g,
                        const float* __restrict__ mu_l, const float* __restrict__ rstd_l,
                        const float* __restrict__ alpha,
                        const float* __restrict__ scale, const float* __restrict__ bias,
                        float* __restrict__ out) {
    int idx = blockIdx.x * 256 + threadIdx.x;
    int c = idx & 31;
    int l = (idx >> 5) & (LL - 1);
    int b = idx >> 18;                  // 2^18 = L*C
    // tok_per_time closed form (argmin over centers 8n+8, first-index ties)
    int n = (l >= 5) ? min((l - 5) >> 3, NTOK - 1) : 0;

    float xv  = x[idx];
    int gbc   = b * 32 + c;
    float xg  = (xv - mu_g[gbc]) * rstd_g[gbc];
    int o     = (b * NTOK + n) * CC + c;
    float xl  = (xv - mu_l[o]) * rstd_l[o];
    xg = fminf(fmaxf(xg, -30.0f), 30.0f);
    xl = fminf(fmaxf(xl, -30.0f), 30.0f);
    float a   = alpha[gbc * NTOK + n];  // [b][c][n] layout
    float y   = a * xl + (1.0f - a) * xg;
    out[idx]  = y * scale[c] + bias[c];
}

extern "C" void kernel_launch(void* const* d_in, const int* in_sizes, int n_in,
                              void* d_out, int out_size, void* d_ws, size_t ws_size,
                              hipStream_t stream) {
    const float* x    = (const float*)d_in[0];
    const float* ff   = (const float*)d_in[1];
    const float* aw1  = (const float*)d_in[2];
    const float* ab1  = (const float*)d_in[3];
    const float* aw2  = (const float*)d_in[4];
    const float* ab2  = (const float*)d_in[5];
    // d_in[6..9] = beta weights: dead code in the reference output
    const float* scal = (const float*)d_in[10];
    const float* bias = (const float*)d_in[11];
    float* out = (float*)d_out;

    float* wsf    = (float*)d_ws;
    float* ps     = wsf;                       //  8192
    float* pq     = wsf + 8192;                //  8192
    float* mu_g   = wsf + 16384;               //  1024
    float* rstd_g = wsf + 17408;               //  1024
    float* mu_l   = wsf + 18432;               //  1047552
    float* rstd_l = wsf + 18432 + 1047552;     //  1047552
    float* alpha  = wsf + 18432 + 2 * 1047552; //  1047552
    // total 3,161,088 floats = 12.06 MB of d_ws

    k1_partial<<<BB * 8, 256, 0, stream>>>(x, ps, pq);
    k1b_final<<<1, 1024, 0, stream>>>(ps, pq, mu_g, rstd_g);
    k2_tok<<<BB * 128, 256, 0, stream>>>(x, mu_l, rstd_l);
    k3_alpha<<<4092, 256, 0, stream>>>(ff, aw1, ab1, aw2, ab2, alpha);
    k4_main<<<32768, 256, 0, stream>>>(x, mu_g, rstd_g, mu_l, rstd_l, alpha,
                                       scal, bias, out);
}

// Round 3
// 93.716 us; speedup vs baseline: 3.5970x; 1.2365x over previous
//
#include <hip/hip_runtime.h>
#include <math.h>

// Problem constants (fixed by harness)
#define BB   32
#define LL   8192
#define CC   32
#define NTOK 1023      // (L-16)/8 + 1
#define KK   16
#define HID  32

// ---------------- K1: per-(b,c) partial sums over an L/8 slice ----------------
__global__ void k1_partial(const float* __restrict__ x,
                           float* __restrict__ ps, float* __restrict__ pq) {
    int b  = blockIdx.x >> 3;
    int sl = blockIdx.x & 7;
    int c  = threadIdx.x & 31;
    int g  = threadIdx.x >> 5;
    const float* xb = x + (size_t)b * LL * CC;
    float s = 0.f, q = 0.f;
    int l0 = sl * 1024;
    for (int l = l0 + g; l < l0 + 1024; l += 8) {
        float v = xb[(size_t)l * CC + c];
        s += v; q += v * v;
    }
    __shared__ float ls[256], lq[256];
    ls[threadIdx.x] = s; lq[threadIdx.x] = q;
    __syncthreads();
    for (int off = 128; off >= 32; off >>= 1) {
        if (threadIdx.x < off) {
            ls[threadIdx.x] += ls[threadIdx.x + off];
            lq[threadIdx.x] += lq[threadIdx.x + off];
        }
        __syncthreads();
    }
    if (threadIdx.x < 32) {
        ps[blockIdx.x * 32 + c] = ls[c];
        pq[blockIdx.x * 32 + c] = lq[c];
    }
}

// ---------------- K1b: finish global stats ----------------
__global__ void k1b_final(const float* __restrict__ ps, const float* __restrict__ pq,
                          float* __restrict__ mu_g, float* __restrict__ rstd_g) {
    int t = threadIdx.x;           // t = b*32 + c
    float s = 0.f, q = 0.f;
    int b = t >> 5, c = t & 31;
    for (int sl = 0; sl < 8; ++sl) {
        s += ps[(b * 8 + sl) * 32 + c];
        q += pq[(b * 8 + sl) * 32 + c];
    }
    float mu  = s * (1.0f / LL);
    float var = fmaxf(q * (1.0f / LL) - mu * mu, 1e-4f);
    mu_g[t]   = mu;
    rstd_g[t] = 1.0f / sqrtf(var);
}

// ---------------- K2: token-local stats ([b][n][c] layout) ----------------
__global__ void k2_tok(const float* __restrict__ x,
                       float* __restrict__ mu_l, float* __restrict__ rstd_l) {
    int nb = blockIdx.x & 127;
    int b  = blockIdx.x >> 7;
    int c  = threadIdx.x & 31;
    int nl = threadIdx.x >> 5;
    int n  = nb * 8 + nl;
    if (n >= NTOK) return;
    const float* xp = x + ((size_t)b * LL + n * 8) * CC + c;
    float s = 0.f, q = 0.f;
#pragma unroll
    for (int p = 0; p < 16; ++p) {
        float v = xp[(size_t)p * CC];
        s += v; q += v * v;
    }
    float mu  = s * (1.0f / 16.0f);
    float var = fmaxf(q * (1.0f / 16.0f) - mu * mu, 1e-4f);
    int o = (b * NTOK + n) * CC + c;
    mu_l[o]   = mu;
    rstd_l[o] = 1.0f / sqrtf(var);
}

// ---------------- K3: alpha gate MLP ----------------
// 2 rows/thread; w1 transposed in LDS -> 4x ds_read_b128 per hidden unit
// (was 512 scalar ds_read_b32 per row = LDS-issue-bound).
// Cheap gelu: gelu(h) = h * sigmoid(1.59577h + 0.0713548h^3), one exp2 + rcp.
__global__ void __launch_bounds__(256, 2)
k3_alpha(const float* __restrict__ ff,
         const float* __restrict__ w1, const float* __restrict__ b1,
         const float* __restrict__ w2, const float* __restrict__ b2,
         float* __restrict__ alpha) {
    __shared__ float4 w1t4[HID * 4];   // w1t[j][k] : [32][16] floats
    __shared__ float2 bw[HID];         // (b1[j], w2[j])
    __shared__ float  b2s;
    int t = threadIdx.x;
    for (int i = t; i < KK * HID; i += 256) {
        int j = i >> 4, k = i & 15;
        ((float*)w1t4)[i] = w1[k * HID + j];
    }
    if (t < HID) bw[t] = make_float2(b1[t], w2[t]);
    if (t == 0)  b2s = b2[0];
    __syncthreads();

    int r0 = blockIdx.x * 512 + t;     // grid 2046 * 512 rows = 1,047,552 exactly
    int r1 = r0 + 256;
    float f0[KK], f1[KK];
    const float4* p0 = (const float4*)(ff + (size_t)r0 * KK);
    const float4* p1 = (const float4*)(ff + (size_t)r1 * KK);
#pragma unroll
    for (int v = 0; v < 4; ++v) {
        float4 a = p0[v];
        f0[4*v] = a.x; f0[4*v+1] = a.y; f0[4*v+2] = a.z; f0[4*v+3] = a.w;
    }
#pragma unroll
    for (int v = 0; v < 4; ++v) {
        float4 a = p1[v];
        f1[4*v] = a.x; f1[4*v+1] = a.y; f1[4*v+2] = a.z; f1[4*v+3] = a.w;
    }

    const float C0 = -2.302211325f;    // -1.5957691216 * log2(e)
    const float C1 = -0.102943702f;    // -0.0713548162 * log2(e)
    float out0 = b2s, out1 = b2s;
#pragma unroll
    for (int j = 0; j < HID; ++j) {
        float2 bwj = bw[j];
        float h0 = bwj.x, h1 = bwj.x;
#pragma unroll
        for (int q = 0; q < 4; ++q) {
            float4 w = w1t4[j * 4 + q];
            h0 = fmaf(f0[4*q  ], w.x, h0); h1 = fmaf(f1[4*q  ], w.x, h1);
            h0 = fmaf(f0[4*q+1], w.y, h0); h1 = fmaf(f1[4*q+1], w.y, h1);
            h0 = fmaf(f0[4*q+2], w.z, h0); h1 = fmaf(f1[4*q+2], w.z, h1);
            h0 = fmaf(f0[4*q+3], w.w, h0); h1 = fmaf(f1[4*q+3], w.w, h1);
        }
        float t0 = h0 * h0,            t1 = h1 * h1;
        float a0 = fmaf(t0, C1, C0),   a1 = fmaf(t1, C1, C0);
        float e0 = exp2f(a0 * h0),     e1 = exp2f(a1 * h1);
        float g0 = h0 * __builtin_amdgcn_rcpf(1.0f + e0);
        float g1 = h1 * __builtin_amdgcn_rcpf(1.0f + e1);
        out0 = fmaf(g0, bwj.y, out0);
        out1 = fmaf(g1, bwj.y, out1);
    }
    alpha[r0] = __builtin_amdgcn_rcpf(1.0f + exp2f(-1.44269504f * out0));
    alpha[r1] = __builtin_amdgcn_rcpf(1.0f + exp2f(-1.44269504f * out1));
}

// ---------------- K3b: transpose alpha [b][c][n] -> [b][n][c] ----------------
// grid = B * 32 (n-tiles of 32), block 256; both sides coalesced via LDS tile.
__global__ void k3b_transpose(const float* __restrict__ a_bcn,
                              float* __restrict__ a_bnc) {
    __shared__ float tile[32][33];
    int b  = blockIdx.x >> 5;
    int n0 = (blockIdx.x & 31) * 32;
    int tn = threadIdx.x & 31;
    int tc = threadIdx.x >> 5;
#pragma unroll
    for (int i = 0; i < 4; ++i) {
        int c = tc + 8 * i;
        int n = n0 + tn;
        float v = 0.f;
        if (n < NTOK) v = a_bcn[((size_t)(b * CC + c)) * NTOK + n];
        tile[c][tn] = v;
    }
    __syncthreads();
#pragma unroll
    for (int i = 0; i < 4; ++i) {
        int n = n0 + tc + 8 * i;
        if (n < NTOK) a_bnc[((size_t)(b * NTOK + n)) * CC + tn] = tile[tn][tc + 8 * i];
    }
}

// ---------------- K4: fused normalize + mix + affine (float4) ----------------
// i4 = global float4 index; c4 = i4&7, l = (i4>>3)&8191, b = i4>>16
__global__ void k4_main(const float4* __restrict__ x4,
                        const float4* __restrict__ mug4, const float4* __restrict__ rsg4,
                        const float4* __restrict__ mul4, const float4* __restrict__ rsl4,
                        const float4* __restrict__ al4,
                        const float4* __restrict__ sc4, const float4* __restrict__ bi4,
                        float4* __restrict__ out4) {
    int i4 = blockIdx.x * 256 + threadIdx.x;
    int c4 = i4 & 7;
    int l  = (i4 >> 3) & (LL - 1);
    int b  = i4 >> 16;                  // L*C/4 = 65536
    int n  = (l >= 5) ? min((l - 5) >> 3, NTOK - 1) : 0;

    float4 xv = x4[i4];
    int g4 = b * 8 + c4;
    float4 mg = mug4[g4], rg = rsg4[g4];
    int o4 = (b * NTOK + n) * 8 + c4;
    float4 ml = mul4[o4], rl = rsl4[o4], av = al4[o4];
    float4 s  = sc4[c4],  bi = bi4[c4];

    float4 y;
    {
        float xg = fminf(fmaxf((xv.x - mg.x) * rg.x, -30.f), 30.f);
        float xl = fminf(fmaxf((xv.x - ml.x) * rl.x, -30.f), 30.f);
        y.x = fmaf(av.x, xl - xg, xg) * s.x + bi.x;
    }
    {
        float xg = fminf(fmaxf((xv.y - mg.y) * rg.y, -30.f), 30.f);
        float xl = fminf(fmaxf((xv.y - ml.y) * rl.y, -30.f), 30.f);
        y.y = fmaf(av.y, xl - xg, xg) * s.y + bi.y;
    }
    {
        float xg = fminf(fmaxf((xv.z - mg.z) * rg.z, -30.f), 30.f);
        float xl = fminf(fmaxf((xv.z - ml.z) * rl.z, -30.f), 30.f);
        y.z = fmaf(av.z, xl - xg, xg) * s.z + bi.z;
    }
    {
        float xg = fminf(fmaxf((xv.w - mg.w) * rg.w, -30.f), 30.f);
        float xl = fminf(fmaxf((xv.w - ml.w) * rl.w, -30.f), 30.f);
        y.w = fmaf(av.w, xl - xg, xg) * s.w + bi.w;
    }
    out4[i4] = y;
}

extern "C" void kernel_launch(void* const* d_in, const int* in_sizes, int n_in,
                              void* d_out, int out_size, void* d_ws, size_t ws_size,
                              hipStream_t stream) {
    const float* x    = (const float*)d_in[0];
    const float* ff   = (const float*)d_in[1];
    const float* aw1  = (const float*)d_in[2];
    const float* ab1  = (const float*)d_in[3];
    const float* aw2  = (const float*)d_in[4];
    const float* ab2  = (const float*)d_in[5];
    // d_in[6..9] = beta weights: dead code in the reference output
    const float* scal = (const float*)d_in[10];
    const float* bias = (const float*)d_in[11];
    float* out = (float*)d_out;

    float* wsf     = (float*)d_ws;
    float* ps      = wsf;                        //    8192
    float* pq      = wsf + 8192;                 //    8192
    float* mu_g    = wsf + 16384;                //    1024
    float* rstd_g  = wsf + 17408;                //    1024
    float* mu_l    = wsf + 18432;                // 1047552
    float* rstd_l  = mu_l    + 1047552;          // 1047552
    float* alpha_a = rstd_l  + 1047552;          // 1047552  ([b][c][n])
    float* alpha_t = alpha_a + 1047552;          // 1047552  ([b][n][c])
    // total 4,208,640 floats = 16.05 MB of d_ws

    k1_partial<<<BB * 8, 256, 0, stream>>>(x, ps, pq);
    k1b_final<<<1, 1024, 0, stream>>>(ps, pq, mu_g, rstd_g);
    k2_tok<<<BB * 128, 256, 0, stream>>>(x, mu_l, rstd_l);
    k3_alpha<<<2046, 256, 0, stream>>>(ff, aw1, ab1, aw2, ab2, alpha_a);
    k3b_transpose<<<BB * 32, 256, 0, stream>>>(alpha_a, alpha_t);
    k4_main<<<8192, 256, 0, stream>>>((const float4*)x,
                                      (const float4*)mu_g, (const float4*)rstd_g,
                                      (const float4*)mu_l, (const float4*)rstd_l,
                                      (const float4*)alpha_t,
                                      (const float4*)scal, (const float4*)bias,
                                      (float4*)out);
}

// Round 4
// 66.214 us; speedup vs baseline: 5.0910x; 1.4153x over previous
//
#include <hip/hip_runtime.h>
#include <math.h>

// Problem constants (fixed by harness)
#define BB   32
#define LL   8192
#define CC   32
#define NTOK 1023      // (L-16)/8 + 1
#define KK   16
#define HID  32

// ---------------- K12: fused global-partial + token-local stats ----------------
// grid = B*32 (slice of 256 rows + 8-row halo), block = 256.
// Stages slice in LDS (33.8 KB -> 4 blocks/CU), reads x ONCE for both stats.
// (Old k1: 256 blocks, VGPR=8 -> 1 load in flight, 128 serial latencies = 56us.)
__global__ void __launch_bounds__(256)
k12_stats(const float* __restrict__ x,
          float* __restrict__ ps, float* __restrict__ pq,
          float* __restrict__ mu_l, float* __restrict__ rstd_l) {
    __shared__ float xs[264 * 32];         // [row][c]
    __shared__ float ls[256], lq[256];
    int b  = blockIdx.x >> 5;
    int s  = blockIdx.x & 31;
    int l0 = s * 256;
    int t  = threadIdx.x;

    const float4* xp4 = (const float4*)x + ((size_t)b * LL + l0) * 8;
    float4* xs4 = (float4*)xs;
#pragma unroll
    for (int it = 0; it < 8; ++it) {       // 2048 float4 = 256 rows, 8 in flight
        int i = t + it * 256;
        xs4[i] = xp4[i];
    }
    if (s < 31 && t < 64)                  // 8-row halo for boundary tokens
        xs4[2048 + t] = xp4[2048 + t];
    __syncthreads();

    int c = t & 31, rg = t >> 5;

    // (a) global partial sums over rows 0..255 (each row exactly once chip-wide)
    float s0 = 0.f, q0 = 0.f;
#pragma unroll 8
    for (int r = rg; r < 256; r += 8) {
        float v = xs[r * 32 + c];
        s0 += v; q0 += v * v;
    }
    ls[t] = s0; lq[t] = q0;

    // (b) token stats: tokens n = s*32 + nl, nl = rg + 8*batch, rows 8nl..8nl+15
#pragma unroll
    for (int batch = 0; batch < 4; ++batch) {
        int nl = rg + 8 * batch;
        int n  = s * 32 + nl;
        if (n < NTOK) {
            float ss = 0.f, qq = 0.f;
#pragma unroll
            for (int p = 0; p < 16; ++p) {
                float v = xs[(8 * nl + p) * 32 + c];
                ss += v; qq += v * v;
            }
            float mu  = ss * (1.0f / 16.0f);
            float var = fmaxf(qq * (1.0f / 16.0f) - mu * mu, 1e-4f);
            int o = (b * NTOK + n) * CC + c;
            mu_l[o]   = mu;
            rstd_l[o] = 1.0f / sqrtf(var);
        }
    }

    __syncthreads();
    for (int off = 128; off >= 32; off >>= 1) {
        if (t < off) { ls[t] += ls[t + off]; lq[t] += lq[t + off]; }
        __syncthreads();
    }
    if (t < 32) {
        ps[blockIdx.x * 32 + c] = ls[c];   // index = (b*32+s)*32 + c
        pq[blockIdx.x * 32 + c] = lq[c];
    }
}

// ---------------- K1b: finish global stats (reduce 32 slices) ----------------
__global__ void k1b_final(const float* __restrict__ ps, const float* __restrict__ pq,
                          float* __restrict__ mu_g, float* __restrict__ rstd_g) {
    int t = threadIdx.x;           // t = b*32 + c
    int b = t >> 5, c = t & 31;
    float s = 0.f, q = 0.f;
#pragma unroll 8
    for (int sl = 0; sl < 32; ++sl) {
        s += ps[(b * 32 + sl) * 32 + c];
        q += pq[(b * 32 + sl) * 32 + c];
    }
    float mu  = s * (1.0f / LL);
    float var = fmaxf(q * (1.0f / LL) - mu * mu, 1e-4f);
    mu_g[t]   = mu;
    rstd_g[t] = 1.0f / sqrtf(var);
}

// ---------------- K3: alpha gate MLP ----------------
// 2 rows/thread; w1 transposed in LDS -> ds_read_b128; cheap tanh-form gelu.
__global__ void __launch_bounds__(256, 2)
k3_alpha(const float* __restrict__ ff,
         const float* __restrict__ w1, const float* __restrict__ b1,
         const float* __restrict__ w2, const float* __restrict__ b2,
         float* __restrict__ alpha) {
    __shared__ float4 w1t4[HID * 4];   // w1t[j][k] : [32][16] floats
    __shared__ float2 bw[HID];         // (b1[j], w2[j])
    __shared__ float  b2s;
    int t = threadIdx.x;
    for (int i = t; i < KK * HID; i += 256) {
        int j = i >> 4, k = i & 15;
        ((float*)w1t4)[i] = w1[k * HID + j];
    }
    if (t < HID) bw[t] = make_float2(b1[t], w2[t]);
    if (t == 0)  b2s = b2[0];
    __syncthreads();

    int r0 = blockIdx.x * 512 + t;     // grid 2046 * 512 rows = 1,047,552 exactly
    int r1 = r0 + 256;
    float f0[KK], f1[KK];
    const float4* p0 = (const float4*)(ff + (size_t)r0 * KK);
    const float4* p1 = (const float4*)(ff + (size_t)r1 * KK);
#pragma unroll
    for (int v = 0; v < 4; ++v) {
        float4 a = p0[v];
        f0[4*v] = a.x; f0[4*v+1] = a.y; f0[4*v+2] = a.z; f0[4*v+3] = a.w;
    }
#pragma unroll
    for (int v = 0; v < 4; ++v) {
        float4 a = p1[v];
        f1[4*v] = a.x; f1[4*v+1] = a.y; f1[4*v+2] = a.z; f1[4*v+3] = a.w;
    }

    const float C0 = -2.302211325f;    // -1.5957691216 * log2(e)
    const float C1 = -0.102943702f;    // -0.0713548162 * log2(e)
    float out0 = b2s, out1 = b2s;
#pragma unroll
    for (int j = 0; j < HID; ++j) {
        float2 bwj = bw[j];
        float h0 = bwj.x, h1 = bwj.x;
#pragma unroll
        for (int q = 0; q < 4; ++q) {
            float4 w = w1t4[j * 4 + q];
            h0 = fmaf(f0[4*q  ], w.x, h0); h1 = fmaf(f1[4*q  ], w.x, h1);
            h0 = fmaf(f0[4*q+1], w.y, h0); h1 = fmaf(f1[4*q+1], w.y, h1);
            h0 = fmaf(f0[4*q+2], w.z, h0); h1 = fmaf(f1[4*q+2], w.z, h1);
            h0 = fmaf(f0[4*q+3], w.w, h0); h1 = fmaf(f1[4*q+3], w.w, h1);
        }
        float t0 = h0 * h0,            t1 = h1 * h1;
        float a0 = fmaf(t0, C1, C0),   a1 = fmaf(t1, C1, C0);
        float e0 = exp2f(a0 * h0),     e1 = exp2f(a1 * h1);
        float g0 = h0 * __builtin_amdgcn_rcpf(1.0f + e0);
        float g1 = h1 * __builtin_amdgcn_rcpf(1.0f + e1);
        out0 = fmaf(g0, bwj.y, out0);
        out1 = fmaf(g1, bwj.y, out1);
    }
    alpha[r0] = __builtin_amdgcn_rcpf(1.0f + exp2f(-1.44269504f * out0));
    alpha[r1] = __builtin_amdgcn_rcpf(1.0f + exp2f(-1.44269504f * out1));
}

// ---------------- K3b: transpose alpha [b][c][n] -> [b][n][c] ----------------
__global__ void k3b_transpose(const float* __restrict__ a_bcn,
                              float* __restrict__ a_bnc) {
    __shared__ float tile[32][33];
    int b  = blockIdx.x >> 5;
    int n0 = (blockIdx.x & 31) * 32;
    int tn = threadIdx.x & 31;
    int tc = threadIdx.x >> 5;
#pragma unroll
    for (int i = 0; i < 4; ++i) {
        int c = tc + 8 * i;
        int n = n0 + tn;
        float v = 0.f;
        if (n < NTOK) v = a_bcn[((size_t)(b * CC + c)) * NTOK + n];
        tile[c][tn] = v;
    }
    __syncthreads();
#pragma unroll
    for (int i = 0; i < 4; ++i) {
        int n = n0 + tc + 8 * i;
        if (n < NTOK) a_bnc[((size_t)(b * NTOK + n)) * CC + tn] = tile[tn][tc + 8 * i];
    }
}

// ---------------- K4: fused normalize + mix + affine (float4) ----------------
__global__ void k4_main(const float4* __restrict__ x4,
                        const float4* __restrict__ mug4, const float4* __restrict__ rsg4,
                        const float4* __restrict__ mul4, const float4* __restrict__ rsl4,
                        const float4* __restrict__ al4,
                        const float4* __restrict__ sc4, const float4* __restrict__ bi4,
                        float4* __restrict__ out4) {
    int i4 = blockIdx.x * 256 + threadIdx.x;
    int c4 = i4 & 7;
    int l  = (i4 >> 3) & (LL - 1);
    int b  = i4 >> 16;                  // L*C/4 = 65536
    int n  = (l >= 5) ? min((l - 5) >> 3, NTOK - 1) : 0;

    float4 xv = x4[i4];
    int g4 = b * 8 + c4;
    float4 mg = mug4[g4], rg = rsg4[g4];
    int o4 = (b * NTOK + n) * 8 + c4;
    float4 ml = mul4[o4], rl = rsl4[o4], av = al4[o4];
    float4 s  = sc4[c4],  bi = bi4[c4];

    float4 y;
    {
        float xg = fminf(fmaxf((xv.x - mg.x) * rg.x, -30.f), 30.f);
        float xl = fminf(fmaxf((xv.x - ml.x) * rl.x, -30.f), 30.f);
        y.x = fmaf(av.x, xl - xg, xg) * s.x + bi.x;
    }
    {
        float xg = fminf(fmaxf((xv.y - mg.y) * rg.y, -30.f), 30.f);
        float xl = fminf(fmaxf((xv.y - ml.y) * rl.y, -30.f), 30.f);
        y.y = fmaf(av.y, xl - xg, xg) * s.y + bi.y;
    }
    {
        float xg = fminf(fmaxf((xv.z - mg.z) * rg.z, -30.f), 30.f);
        float xl = fminf(fmaxf((xv.z - ml.z) * rl.z, -30.f), 30.f);
        y.z = fmaf(av.z, xl - xg, xg) * s.z + bi.z;
    }
    {
        float xg = fminf(fmaxf((xv.w - mg.w) * rg.w, -30.f), 30.f);
        float xl = fminf(fmaxf((xv.w - ml.w) * rl.w, -30.f), 30.f);
        y.w = fmaf(av.w, xl - xg, xg) * s.w + bi.w;
    }
    out4[i4] = y;
}

extern "C" void kernel_launch(void* const* d_in, const int* in_sizes, int n_in,
                              void* d_out, int out_size, void* d_ws, size_t ws_size,
                              hipStream_t stream) {
    const float* x    = (const float*)d_in[0];
    const float* ff   = (const float*)d_in[1];
    const float* aw1  = (const float*)d_in[2];
    const float* ab1  = (const float*)d_in[3];
    const float* aw2  = (const float*)d_in[4];
    const float* ab2  = (const float*)d_in[5];
    // d_in[6..9] = beta weights: dead code in the reference output
    const float* scal = (const float*)d_in[10];
    const float* bias = (const float*)d_in[11];
    float* out = (float*)d_out;

    float* wsf     = (float*)d_ws;
    float* ps      = wsf;                        //   32768 ((b,s,c))
    float* pq      = wsf + 32768;                //   32768
    float* mu_g    = wsf + 65536;                //    1024
    float* rstd_g  = wsf + 66560;                //    1024
    float* mu_l    = wsf + 67584;                // 1047552
    float* rstd_l  = mu_l    + 1047552;          // 1047552
    float* alpha_a = rstd_l  + 1047552;          // 1047552  ([b][c][n])
    float* alpha_t = alpha_a + 1047552;          // 1047552  ([b][n][c])
    // total 4,257,792 floats = 16.24 MB of d_ws

    k12_stats<<<BB * 32, 256, 0, stream>>>(x, ps, pq, mu_l, rstd_l);
    k1b_final<<<1, 1024, 0, stream>>>(ps, pq, mu_g, rstd_g);
    k3_alpha<<<2046, 256, 0, stream>>>(ff, aw1, ab1, aw2, ab2, alpha_a);
    k3b_transpose<<<BB * 32, 256, 0, stream>>>(alpha_a, alpha_t);
    k4_main<<<8192, 256, 0, stream>>>((const float4*)x,
                                      (const float4*)mu_g, (const float4*)rstd_g,
                                      (const float4*)mu_l, (const float4*)rstd_l,
                                      (const float4*)alpha_t,
                                      (const float4*)scal, (const float4*)bias,
                                      (float4*)out);
}

// Round 5
// 57.509 us; speedup vs baseline: 5.8615x; 1.1514x over previous
//
#include <hip/hip_runtime.h>
#include <math.h>

// Problem constants (fixed by harness)
#define BB   32
#define LL   8192
#define CC   32
#define NTOK 1023      // (L-16)/8 + 1
#define KK   16
#define HID  32

// ---------------- Fused K12+K3 ----------------
// Blocks 0..1023  : stats part — (b = blk>>5, s = blk&31): stage 256(+8 halo)
//                   rows in LDS, emit global partial sums + 32 token stats.
// Blocks 1024..3071: alpha part — (b, 16-token tile) x 32 channels = 512 MLP
//                   rows, 2/thread; write alpha DIRECTLY in [b][n][c] (the old
//                   separate transpose kernel is gone). No data dependence
//                   between the two parts -> safe in one dispatch, and the
//                   VALU-heavy alpha blocks overlap the BW-heavy stats blocks.
__global__ void __launch_bounds__(256)
k_fused(const float* __restrict__ x, const float* __restrict__ ff,
        const float* __restrict__ w1, const float* __restrict__ b1,
        const float* __restrict__ w2, const float* __restrict__ b2,
        float* __restrict__ ps, float* __restrict__ pq,
        float* __restrict__ mu_l, float* __restrict__ rstd_l,
        float* __restrict__ alpha_t) {
    __shared__ float smem[9216];   // 36 KB: xs[8448] + ls[256] + lq[256]
    int t = threadIdx.x;

    if (blockIdx.x < 1024) {
        // ================= stats part =================
        float* xs = smem;                  // [264][32]
        float* ls = smem + 8448;
        float* lq = smem + 8704;
        int b  = blockIdx.x >> 5;
        int s  = blockIdx.x & 31;
        const float4* xp4 = (const float4*)x + ((size_t)b * LL + s * 256) * 8;
        float4* xs4 = (float4*)xs;
#pragma unroll
        for (int it = 0; it < 8; ++it) {   // 256 rows, 8 loads in flight
            int i = t + it * 256;
            xs4[i] = xp4[i];
        }
        if (s < 31 && t < 64)              // 8-row halo for boundary tokens
            xs4[2048 + t] = xp4[2048 + t];
        __syncthreads();

        int c = t & 31, rg = t >> 5;

        // (a) global partial sums over rows 0..255
        float s0 = 0.f, q0 = 0.f;
#pragma unroll 8
        for (int r = rg; r < 256; r += 8) {
            float v = xs[r * 32 + c];
            s0 += v; q0 += v * v;
        }
        ls[t] = s0; lq[t] = q0;

        // (b) token stats: n = s*32 + nl, rows 8nl..8nl+15
#pragma unroll
        for (int batch = 0; batch < 4; ++batch) {
            int nl = rg + 8 * batch;
            int n  = s * 32 + nl;
            if (n < NTOK) {
                float ss = 0.f, qq = 0.f;
#pragma unroll
                for (int p = 0; p < 16; ++p) {
                    float v = xs[(8 * nl + p) * 32 + c];
                    ss += v; qq += v * v;
                }
                float mu  = ss * (1.0f / 16.0f);
                float var = fmaxf(qq * (1.0f / 16.0f) - mu * mu, 1e-4f);
                int o = (b * NTOK + n) * CC + c;
                mu_l[o]   = mu;
                rstd_l[o] = 1.0f / sqrtf(var);
            }
        }

        __syncthreads();
        for (int off = 128; off >= 32; off >>= 1) {
            if (t < off) { ls[t] += ls[t + off]; lq[t] += lq[t + off]; }
            __syncthreads();
        }
        if (t < 32) {
            ps[blockIdx.x * 32 + c] = ls[c];
            pq[blockIdx.x * 32 + c] = lq[c];
        }
    } else {
        // ================= alpha part =================
        float*  w1t = smem;                    // [32][16] transposed w1
        float2* bw  = (float2*)(smem + 512);   // (b1[j], w2[j])
        float*  b2s = smem + 576;
        float*  als = smem + 580;              // [32][17] alpha tile (padded)
        int rel  = blockIdx.x - 1024;
        int b    = rel >> 6;
        int n0   = (rel & 63) * 16;
        for (int i = t; i < KK * HID; i += 256) {
            int j = i >> 4, k = i & 15;
            w1t[i] = w1[k * HID + j];
        }
        if (t < HID) bw[t] = make_float2(b1[t], w2[t]);
        if (t == 0)  b2s[0] = b2[0];
        __syncthreads();

        int c0 = t >> 4, c1 = c0 + 16, nl = t & 15;
        int n  = n0 + nl;
        bool valid = (n < NTOK);

        float f0[KK], f1[KK];
        if (valid) {
            const float4* p0 = (const float4*)(ff + ((size_t)(b * CC + c0) * NTOK + n) * KK);
            const float4* p1 = (const float4*)(ff + ((size_t)(b * CC + c1) * NTOK + n) * KK);
#pragma unroll
            for (int v = 0; v < 4; ++v) {
                float4 a = p0[v];
                f0[4*v] = a.x; f0[4*v+1] = a.y; f0[4*v+2] = a.z; f0[4*v+3] = a.w;
            }
#pragma unroll
            for (int v = 0; v < 4; ++v) {
                float4 a = p1[v];
                f1[4*v] = a.x; f1[4*v+1] = a.y; f1[4*v+2] = a.z; f1[4*v+3] = a.w;
            }
        } else {
#pragma unroll
            for (int k = 0; k < KK; ++k) { f0[k] = 0.f; f1[k] = 0.f; }
        }

        const float C0 = -2.302211325f;    // -1.5957691216 * log2(e)
        const float C1 = -0.102943702f;    // -0.0713548162 * log2(e)
        float out0 = b2s[0], out1 = b2s[0];
        const float4* w1t4 = (const float4*)w1t;
#pragma unroll
        for (int j = 0; j < HID; ++j) {
            float2 bwj = bw[j];
            float h0 = bwj.x, h1 = bwj.x;
#pragma unroll
            for (int q = 0; q < 4; ++q) {
                float4 w = w1t4[j * 4 + q];
                h0 = fmaf(f0[4*q  ], w.x, h0); h1 = fmaf(f1[4*q  ], w.x, h1);
                h0 = fmaf(f0[4*q+1], w.y, h0); h1 = fmaf(f1[4*q+1], w.y, h1);
                h0 = fmaf(f0[4*q+2], w.z, h0); h1 = fmaf(f1[4*q+2], w.z, h1);
                h0 = fmaf(f0[4*q+3], w.w, h0); h1 = fmaf(f1[4*q+3], w.w, h1);
            }
            float t0 = h0 * h0,            t1 = h1 * h1;
            float a0 = fmaf(t0, C1, C0),   a1 = fmaf(t1, C1, C0);
            float e0 = exp2f(a0 * h0),     e1 = exp2f(a1 * h1);
            float g0 = h0 * __builtin_amdgcn_rcpf(1.0f + e0);
            float g1 = h1 * __builtin_amdgcn_rcpf(1.0f + e1);
            out0 = fmaf(g0, bwj.y, out0);
            out1 = fmaf(g1, bwj.y, out1);
        }
        als[c0 * 17 + nl] = __builtin_amdgcn_rcpf(1.0f + exp2f(-1.44269504f * out0));
        als[c1 * 17 + nl] = __builtin_amdgcn_rcpf(1.0f + exp2f(-1.44269504f * out1));
        __syncthreads();

        // coalesced [b][n][c] write: 512 contiguous floats, float2 per thread
        int flat = t * 2;
        int nn = flat >> 5, cc = flat & 31;
        if (n0 + nn < NTOK) {
            float2 o;
            o.x = als[cc * 17 + nn];
            o.y = als[(cc + 1) * 17 + nn];
            *(float2*)(alpha_t + ((size_t)(b * NTOK + n0 + nn)) * CC + cc) = o;
        }
    }
}

// ---------------- K1b: finish global stats (reduce 32 slices) ----------------
__global__ void k1b_final(const float* __restrict__ ps, const float* __restrict__ pq,
                          float* __restrict__ mu_g, float* __restrict__ rstd_g) {
    int t = threadIdx.x;           // t = b*32 + c
    int b = t >> 5, c = t & 31;
    float s = 0.f, q = 0.f;
#pragma unroll 8
    for (int sl = 0; sl < 32; ++sl) {
        s += ps[(b * 32 + sl) * 32 + c];
        q += pq[(b * 32 + sl) * 32 + c];
    }
    float mu  = s * (1.0f / LL);
    float var = fmaxf(q * (1.0f / LL) - mu * mu, 1e-4f);
    mu_g[t]   = mu;
    rstd_g[t] = 1.0f / sqrtf(var);
}

// ---------------- K4: fused normalize + mix + affine (float4) ----------------
__global__ void k4_main(const float4* __restrict__ x4,
                        const float4* __restrict__ mug4, const float4* __restrict__ rsg4,
                        const float4* __restrict__ mul4, const float4* __restrict__ rsl4,
                        const float4* __restrict__ al4,
                        const float4* __restrict__ sc4, const float4* __restrict__ bi4,
                        float4* __restrict__ out4) {
    int i4 = blockIdx.x * 256 + threadIdx.x;
    int c4 = i4 & 7;
    int l  = (i4 >> 3) & (LL - 1);
    int b  = i4 >> 16;                  // L*C/4 = 65536
    int n  = (l >= 5) ? min((l - 5) >> 3, NTOK - 1) : 0;

    float4 xv = x4[i4];
    int g4 = b * 8 + c4;
    float4 mg = mug4[g4], rg = rsg4[g4];
    int o4 = (b * NTOK + n) * 8 + c4;
    float4 ml = mul4[o4], rl = rsl4[o4], av = al4[o4];
    float4 s  = sc4[c4],  bi = bi4[c4];

    float4 y;
    {
        float xg = fminf(fmaxf((xv.x - mg.x) * rg.x, -30.f), 30.f);
        float xl = fminf(fmaxf((xv.x - ml.x) * rl.x, -30.f), 30.f);
        y.x = fmaf(av.x, xl - xg, xg) * s.x + bi.x;
    }
    {
        float xg = fminf(fmaxf((xv.y - mg.y) * rg.y, -30.f), 30.f);
        float xl = fminf(fmaxf((xv.y - ml.y) * rl.y, -30.f), 30.f);
        y.y = fmaf(av.y, xl - xg, xg) * s.y + bi.y;
    }
    {
        float xg = fminf(fmaxf((xv.z - mg.z) * rg.z, -30.f), 30.f);
        float xl = fminf(fmaxf((xv.z - ml.z) * rl.z, -30.f), 30.f);
        y.z = fmaf(av.z, xl - xg, xg) * s.z + bi.z;
    }
    {
        float xg = fminf(fmaxf((xv.w - mg.w) * rg.w, -30.f), 30.f);
        float xl = fminf(fmaxf((xv.w - ml.w) * rl.w, -30.f), 30.f);
        y.w = fmaf(av.w, xl - xg, xg) * s.w + bi.w;
    }
    out4[i4] = y;
}

extern "C" void kernel_launch(void* const* d_in, const int* in_sizes, int n_in,
                              void* d_out, int out_size, void* d_ws, size_t ws_size,
                              hipStream_t stream) {
    const float* x    = (const float*)d_in[0];
    const float* ff   = (const float*)d_in[1];
    const float* aw1  = (const float*)d_in[2];
    const float* ab1  = (const float*)d_in[3];
    const float* aw2  = (const float*)d_in[4];
    const float* ab2  = (const float*)d_in[5];
    // d_in[6..9] = beta weights: dead code in the reference output
    const float* scal = (const float*)d_in[10];
    const float* bias = (const float*)d_in[11];
    float* out = (float*)d_out;

    float* wsf     = (float*)d_ws;
    float* ps      = wsf;                        //   32768 ((b,s,c))
    float* pq      = wsf + 32768;                //   32768
    float* mu_g    = wsf + 65536;                //    1024
    float* rstd_g  = wsf + 66560;                //    1024
    float* mu_l    = wsf + 67584;                // 1047552
    float* rstd_l  = mu_l    + 1047552;          // 1047552
    float* alpha_t = rstd_l  + 1047552;          // 1047552  ([b][n][c])
    // total 3,210,240 floats = 12.25 MB of d_ws

    k_fused<<<3072, 256, 0, stream>>>(x, ff, aw1, ab1, aw2, ab2,
                                      ps, pq, mu_l, rstd_l, alpha_t);
    k1b_final<<<1, 1024, 0, stream>>>(ps, pq, mu_g, rstd_g);
    k4_main<<<8192, 256, 0, stream>>>((const float4*)x,
                                      (const float4*)mu_g, (const float4*)rstd_g,
                                      (const float4*)mu_l, (const float4*)rstd_l,
                                      (const float4*)alpha_t,
                                      (const float4*)scal, (const float4*)bias,
                                      (float4*)out);
}

// Round 6
// 57.362 us; speedup vs baseline: 5.8766x; 1.0026x over previous
//
#include <hip/hip_runtime.h>
#include <math.h>

// Problem constants (fixed by harness)
#define BB   32
#define LL   8192
#define CC   32
#define NTOK 1023      // (L-16)/8 + 1
#define KK   16
#define HID  32

__device__ __forceinline__ float4 f4add(float4 a, float4 b) {
    return make_float4(a.x + b.x, a.y + b.y, a.z + b.z, a.w + b.w);
}
__device__ __forceinline__ float4 f4fma(float4 a, float4 b, float4 c) {
    return make_float4(fmaf(a.x, b.x, c.x), fmaf(a.y, b.y, c.y),
                       fmaf(a.z, b.z, c.z), fmaf(a.w, b.w, c.w));
}
__device__ __forceinline__ float4 shflx4(float4 v, int m) {
    return make_float4(__shfl_xor(v.x, m, 64), __shfl_xor(v.y, m, 64),
                       __shfl_xor(v.z, m, 64), __shfl_xor(v.w, m, 64));
}

// ---------------- Fused stats + alpha kernel ----------------
// Blocks 0..1023   : stats — (b,s-slice of 256 rows). NO x staging in LDS:
//                    per-thread register partials (c4 = t&7 channel-quad,
//                    rgrp = t>>3 = 8 rows), token stats from 8KB LDS partials
//                    (token nl = rgrp nl + rgrp nl+1, halo via wave-0 shuffle),
//                    global sums via shfl_xor + 1KB scratch.
//                    Old version staged 33.8KB -> whole kernel at 4 blocks/CU
//                    (Occupancy 34%); now smem = 9.5KB -> 8 blocks/CU.
// Blocks 1024..3071: alpha MLP — (b, 16-token tile) x 32 ch, written [b][n][c].
__global__ void __launch_bounds__(256)
k_fused(const float* __restrict__ x, const float* __restrict__ ff,
        const float* __restrict__ w1, const float* __restrict__ b1,
        const float* __restrict__ w2, const float* __restrict__ b2,
        float* __restrict__ ps, float* __restrict__ pq,
        float* __restrict__ mu_l, float* __restrict__ rstd_l,
        float* __restrict__ alpha_t) {
    __shared__ float4 smem4[592];          // 9472 B, union of both parts
    int t = threadIdx.x;

    if (blockIdx.x < 1024) {
        // ================= stats part =================
        float4* part_s = smem4;            // [32 rgrp][8 c4]
        float4* part_q = part_s + 256;
        float4* halo_s = part_q + 256;     // [8 c4]
        float4* halo_q = halo_s + 8;
        float4* wred_s = halo_q + 8;       // [4 wave][8 c4]
        float4* wred_q = wred_s + 32;

        int b  = blockIdx.x >> 5;
        int s  = blockIdx.x & 31;
        int c4 = t & 7, rgrp = t >> 3;
        const float4* xb = (const float4*)x + ((size_t)b * LL + s * 256) * 8;

        // 8 rows x 4 channels in registers (8 loads in flight)
        float4 v[8];
#pragma unroll
        for (int k = 0; k < 8; ++k)
            v[k] = xb[(rgrp * 8 + k) * 8 + c4];
        float4 s4 = make_float4(0.f, 0.f, 0.f, 0.f);
        float4 q4 = make_float4(0.f, 0.f, 0.f, 0.f);
#pragma unroll
        for (int k = 0; k < 8; ++k) {
            s4 = f4add(s4, v[k]);
            q4 = f4fma(v[k], v[k], q4);
        }
        part_s[t] = s4;                    // t == rgrp*8 + c4
        part_q[t] = q4;

        // halo: 8 rows after the slice (wave 0 only; zeros for s==31)
        if (t < 64) {
            float4 hs = make_float4(0.f, 0.f, 0.f, 0.f);
            float4 hq = make_float4(0.f, 0.f, 0.f, 0.f);
            if (s < 31) {
                float4 hv = xb[(256 + (t >> 3)) * 8 + c4];
                hs = hv; hq = f4fma(hv, hv, hq);
            }
            hs = f4add(hs, shflx4(hs, 8));  hq = f4add(hq, shflx4(hq, 8));
            hs = f4add(hs, shflx4(hs, 16)); hq = f4add(hq, shflx4(hq, 16));
            hs = f4add(hs, shflx4(hs, 32)); hq = f4add(hq, shflx4(hq, 32));
            if (t < 8) { halo_s[t] = hs; halo_q[t] = hq; }
        }

        // global partials: reduce over rgrp bits (3,4,5 in-wave, then waves)
        float4 gs = s4, gq = q4;
        gs = f4add(gs, shflx4(gs, 8));  gq = f4add(gq, shflx4(gq, 8));
        gs = f4add(gs, shflx4(gs, 16)); gq = f4add(gq, shflx4(gq, 16));
        gs = f4add(gs, shflx4(gs, 32)); gq = f4add(gq, shflx4(gq, 32));
        if ((t & 56) == 0) {               // one lane per (wave, c4)
            wred_s[(t >> 6) * 8 + c4] = gs;
            wred_q[(t >> 6) * 8 + c4] = gq;
        }
        __syncthreads();

        // token stats: token nl = t>>3 needs rgrps nl and nl+1 (32 = halo)
        int nl = t >> 3;
        int n  = s * 32 + nl;
        if (n < NTOK) {
            float4 a  = (nl < 31) ? part_s[(nl + 1) * 8 + c4] : halo_s[c4];
            float4 bq = (nl < 31) ? part_q[(nl + 1) * 8 + c4] : halo_q[c4];
            float4 ts = f4add(part_s[t], a);
            float4 tq = f4add(part_q[t], bq);
            float4 mu = make_float4(ts.x * 0.0625f, ts.y * 0.0625f,
                                    ts.z * 0.0625f, ts.w * 0.0625f);
            float4 var;
            var.x = fmaxf(fmaf(-mu.x, mu.x, tq.x * 0.0625f), 1e-4f);
            var.y = fmaxf(fmaf(-mu.y, mu.y, tq.y * 0.0625f), 1e-4f);
            var.z = fmaxf(fmaf(-mu.z, mu.z, tq.z * 0.0625f), 1e-4f);
            var.w = fmaxf(fmaf(-mu.w, mu.w, tq.w * 0.0625f), 1e-4f);
            float4 rs = make_float4(1.f / sqrtf(var.x), 1.f / sqrtf(var.y),
                                    1.f / sqrtf(var.z), 1.f / sqrtf(var.w));
            size_t o = (size_t)(b * NTOK + n) * 8 + c4;
            ((float4*)mu_l)[o]   = mu;
            ((float4*)rstd_l)[o] = rs;
        }

        // finish global partial write (one float4 per c4)
        if (t < 8) {
            float4 a = f4add(f4add(wred_s[t], wred_s[8 + t]),
                             f4add(wred_s[16 + t], wred_s[24 + t]));
            float4 c = f4add(f4add(wred_q[t], wred_q[8 + t]),
                             f4add(wred_q[16 + t], wred_q[24 + t]));
            ((float4*)ps)[blockIdx.x * 8 + t] = a;
            ((float4*)pq)[blockIdx.x * 8 + t] = c;
        }
    } else {
        // ================= alpha part =================
        float*  smem = (float*)smem4;
        float*  w1t  = smem;                   // [32][16] transposed w1
        float2* bw   = (float2*)(smem + 512);  // (b1[j], w2[j])
        float*  b2s  = smem + 576;
        float*  als  = smem + 580;             // [32][17] alpha tile (padded)
        int rel  = blockIdx.x - 1024;
        int b    = rel >> 6;
        int n0   = (rel & 63) * 16;
        for (int i = t; i < KK * HID; i += 256) {
            int j = i >> 4, k = i & 15;
            w1t[i] = w1[k * HID + j];
        }
        if (t < HID) bw[t] = make_float2(b1[t], w2[t]);
        if (t == 0)  b2s[0] = b2[0];
        __syncthreads();

        int c0 = t >> 4, c1 = c0 + 16, nl = t & 15;
        int n  = n0 + nl;
        bool valid = (n < NTOK);

        float f0[KK], f1[KK];
        if (valid) {
            const float4* p0 = (const float4*)(ff + ((size_t)(b * CC + c0) * NTOK + n) * KK);
            const float4* p1 = (const float4*)(ff + ((size_t)(b * CC + c1) * NTOK + n) * KK);
#pragma unroll
            for (int v = 0; v < 4; ++v) {
                float4 a = p0[v];
                f0[4*v] = a.x; f0[4*v+1] = a.y; f0[4*v+2] = a.z; f0[4*v+3] = a.w;
            }
#pragma unroll
            for (int v = 0; v < 4; ++v) {
                float4 a = p1[v];
                f1[4*v] = a.x; f1[4*v+1] = a.y; f1[4*v+2] = a.z; f1[4*v+3] = a.w;
            }
        } else {
#pragma unroll
            for (int k = 0; k < KK; ++k) { f0[k] = 0.f; f1[k] = 0.f; }
        }

        const float C0 = -2.302211325f;    // -1.5957691216 * log2(e)
        const float C1 = -0.102943702f;    // -0.0713548162 * log2(e)
        float out0 = b2s[0], out1 = b2s[0];
        const float4* w1t4 = (const float4*)w1t;
#pragma unroll
        for (int j = 0; j < HID; ++j) {
            float2 bwj = bw[j];
            float h0 = bwj.x, h1 = bwj.x;
#pragma unroll
            for (int q = 0; q < 4; ++q) {
                float4 w = w1t4[j * 4 + q];
                h0 = fmaf(f0[4*q  ], w.x, h0); h1 = fmaf(f1[4*q  ], w.x, h1);
                h0 = fmaf(f0[4*q+1], w.y, h0); h1 = fmaf(f1[4*q+1], w.y, h1);
                h0 = fmaf(f0[4*q+2], w.z, h0); h1 = fmaf(f1[4*q+2], w.z, h1);
                h0 = fmaf(f0[4*q+3], w.w, h0); h1 = fmaf(f1[4*q+3], w.w, h1);
            }
            float t0 = h0 * h0,            t1 = h1 * h1;
            float a0 = fmaf(t0, C1, C0),   a1 = fmaf(t1, C1, C0);
            float e0 = exp2f(a0 * h0),     e1 = exp2f(a1 * h1);
            float g0 = h0 * __builtin_amdgcn_rcpf(1.0f + e0);
            float g1 = h1 * __builtin_amdgcn_rcpf(1.0f + e1);
            out0 = fmaf(g0, bwj.y, out0);
            out1 = fmaf(g1, bwj.y, out1);
        }
        als[c0 * 17 + nl] = __builtin_amdgcn_rcpf(1.0f + exp2f(-1.44269504f * out0));
        als[c1 * 17 + nl] = __builtin_amdgcn_rcpf(1.0f + exp2f(-1.44269504f * out1));
        __syncthreads();

        // coalesced [b][n][c] write: 512 contiguous floats, float2 per thread
        int flat = t * 2;
        int nn = flat >> 5, cc = flat & 31;
        if (n0 + nn < NTOK) {
            float2 o;
            o.x = als[cc * 17 + nn];
            o.y = als[(cc + 1) * 17 + nn];
            *(float2*)(alpha_t + ((size_t)(b * NTOK + n0 + nn)) * CC + cc) = o;
        }
    }
}

// ---------------- K1b: finish global stats (reduce 32 slices) ----------------
__global__ void k1b_final(const float* __restrict__ ps, const float* __restrict__ pq,
                          float* __restrict__ mu_g, float* __restrict__ rstd_g) {
    int t = threadIdx.x;           // t = b*32 + c
    int b = t >> 5, c = t & 31;
    float s = 0.f, q = 0.f;
#pragma unroll 8
    for (int sl = 0; sl < 32; ++sl) {
        s += ps[(b * 32 + sl) * 32 + c];
        q += pq[(b * 32 + sl) * 32 + c];
    }
    float mu  = s * (1.0f / LL);
    float var = fmaxf(q * (1.0f / LL) - mu * mu, 1e-4f);
    mu_g[t]   = mu;
    rstd_g[t] = 1.0f / sqrtf(var);
}

// ---------------- K4: fused normalize + mix + affine (float4) ----------------
__global__ void k4_main(const float4* __restrict__ x4,
                        const float4* __restrict__ mug4, const float4* __restrict__ rsg4,
                        const float4* __restrict__ mul4, const float4* __restrict__ rsl4,
                        const float4* __restrict__ al4,
                        const float4* __restrict__ sc4, const float4* __restrict__ bi4,
                        float4* __restrict__ out4) {
    int i4 = blockIdx.x * 256 + threadIdx.x;
    int c4 = i4 & 7;
    int l  = (i4 >> 3) & (LL - 1);
    int b  = i4 >> 16;                  // L*C/4 = 65536
    int n  = (l >= 5) ? min((l - 5) >> 3, NTOK - 1) : 0;

    float4 xv = x4[i4];
    int g4 = b * 8 + c4;
    float4 mg = mug4[g4], rg = rsg4[g4];
    int o4 = (b * NTOK + n) * 8 + c4;
    float4 ml = mul4[o4], rl = rsl4[o4], av = al4[o4];
    float4 s  = sc4[c4],  bi = bi4[c4];

    float4 y;
    {
        float xg = fminf(fmaxf((xv.x - mg.x) * rg.x, -30.f), 30.f);
        float xl = fminf(fmaxf((xv.x - ml.x) * rl.x, -30.f), 30.f);
        y.x = fmaf(av.x, xl - xg, xg) * s.x + bi.x;
    }
    {
        float xg = fminf(fmaxf((xv.y - mg.y) * rg.y, -30.f), 30.f);
        float xl = fminf(fmaxf((xv.y - ml.y) * rl.y, -30.f), 30.f);
        y.y = fmaf(av.y, xl - xg, xg) * s.y + bi.y;
    }
    {
        float xg = fminf(fmaxf((xv.z - mg.z) * rg.z, -30.f), 30.f);
        float xl = fminf(fmaxf((xv.z - ml.z) * rl.z, -30.f), 30.f);
        y.z = fmaf(av.z, xl - xg, xg) * s.z + bi.z;
    }
    {
        float xg = fminf(fmaxf((xv.w - mg.w) * rg.w, -30.f), 30.f);
        float xl = fminf(fmaxf((xv.w - ml.w) * rl.w, -30.f), 30.f);
        y.w = fmaf(av.w, xl - xg, xg) * s.w + bi.w;
    }
    out4[i4] = y;
}

extern "C" void kernel_launch(void* const* d_in, const int* in_sizes, int n_in,
                              void* d_out, int out_size, void* d_ws, size_t ws_size,
                              hipStream_t stream) {
    const float* x    = (const float*)d_in[0];
    const float* ff   = (const float*)d_in[1];
    const float* aw1  = (const float*)d_in[2];
    const float* ab1  = (const float*)d_in[3];
    const float* aw2  = (const float*)d_in[4];
    const float* ab2  = (const float*)d_in[5];
    // d_in[6..9] = beta weights: dead code in the reference output
    const float* scal = (const float*)d_in[10];
    const float* bias = (const float*)d_in[11];
    float* out = (float*)d_out;

    float* wsf     = (float*)d_ws;
    float* ps      = wsf;                        //   32768 ((b,s,c))
    float* pq      = wsf + 32768;                //   32768
    float* mu_g    = wsf + 65536;                //    1024
    float* rstd_g  = wsf + 66560;                //    1024
    float* mu_l    = wsf + 67584;                // 1047552
    float* rstd_l  = mu_l    + 1047552;          // 1047552
    float* alpha_t = rstd_l  + 1047552;          // 1047552  ([b][n][c])
    // total 3,210,240 floats = 12.25 MB of d_ws

    k_fused<<<3072, 256, 0, stream>>>(x, ff, aw1, ab1, aw2, ab2,
                                      ps, pq, mu_l, rstd_l, alpha_t);
    k1b_final<<<1, 1024, 0, stream>>>(ps, pq, mu_g, rstd_g);
    k4_main<<<8192, 256, 0, stream>>>((const float4*)x,
                                      (const float4*)mu_g, (const float4*)rstd_g,
                                      (const float4*)mu_l, (const float4*)rstd_l,
                                      (const float4*)alpha_t,
                                      (const float4*)scal, (const float4*)bias,
                                      (float4*)out);
}